// Round 6
// baseline (182.461 us; speedup 1.0000x reference)
//
#include <hip/hip_runtime.h>
#include <hip/hip_fp16.h>
#include <math.h>

typedef _Float16 half8  __attribute__((ext_vector_type(8)));
typedef _Float16 half2v __attribute__((ext_vector_type(2)));
typedef float   floatx4 __attribute__((ext_vector_type(4)));

#define ROWS   16384
#define DIM    128
#define KCODES 8192
#define NSPLIT 8
#define KSPLIT (KCODES / NSPLIT)   // 1024 codes per split
#define NGROUP (KSPLIT / 16)       // 64 groups of 16 codes
#define MTILE  256                 // rows per block (4 waves x 64)
#define DELTA  0.5f                // rescore margin >> pass1 err (~0.02 incl quant)

__device__ __forceinline__ void async_copy16(const void* src, void* dst_lds) {
  __builtin_amdgcn_global_load_lds((const __attribute__((address_space(1))) void*)src,
                                   (__attribute__((address_space(3))) void*)dst_lds,
                                   16, 0, 0);
}

// ---------------- kernel 1: codebook fp16 + e2, LN-once -> xnh ----------------
// Single-term pass-1: only hi fp16 codebook needed (elg dropped).
__global__ __launch_bounds__(256) void prep_kernel(
    const float* __restrict__ cb, const float* __restrict__ x,
    _Float16* __restrict__ ehg, float* __restrict__ e2g,
    _Float16* __restrict__ xnh, float* __restrict__ out_loss)
{
  int tid = threadIdx.x;
  int L = tid & 63;
  int bx = blockIdx.x;
  if (bx == 0 && tid == 0) *out_loss = 0.f;   // gather accumulates atomically
  if (bx < KCODES / 4) {
    int row = bx * 4 + (tid >> 6);
    float2 v = ((const float2*)(cb + (size_t)row * DIM))[L];
    float s2 = v.x * v.x + v.y * v.y;
    #pragma unroll
    for (int m = 1; m < 64; m <<= 1) s2 += __shfl_xor(s2, m);
    if (L == 0) e2g[row] = -0.5f * s2;
    half2v hi = {(_Float16)v.x, (_Float16)v.y};
    ((half2v*)(ehg + (size_t)row * DIM))[L] = hi;
  } else {
    int row = (bx - KCODES / 4) * 4 + (tid >> 6);
    float2 xv = ((const float2*)(x + (size_t)row * DIM))[L];
    float s = xv.x + xv.y;
    #pragma unroll
    for (int m = 1; m < 64; m <<= 1) s += __shfl_xor(s, m);
    float mu = s * (1.0f / 128.0f);
    float dx = xv.x - mu, dy = xv.y - mu;
    float s2 = dx * dx + dy * dy;
    #pragma unroll
    for (int m = 1; m < 64; m <<= 1) s2 += __shfl_xor(s2, m);
    float rstd = 1.0f / sqrtf(s2 * (1.0f / 128.0f) + 1e-5f);
    half2v hv = {(_Float16)(dx * rstd), (_Float16)(dy * rstd)};
    ((half2v*)(xnh + (size_t)row * DIM))[L] = hv;
  }
}

// ---------------- kernel 2: barrier-free argmin ----------------
// r0-r5 post-mortem: dur ~95-100us invariant to MFMA count / staging width /
// barrier+vmcnt flavor => the per-chunk BLOCK barrier itself (all-wave
// reconvergence at ~2 blocks/CU) is the fixed cost. Fix: WAVE-PRIVATE LDS
// rings (3 x 4KB per wave) staged via global_load_lds and synced purely with
// wave-local counted s_waitcnt vmcnt(8) -- NO __syncthreads in the loop.
// Single fp16 term (noise sigma ~4e-3 << in-split top gaps ~1-4; top-2 +
// exact fp32 rescore downstream absorbs it). Packed top-2: acc pre-biased
// to 256-e2/2 (>0), key = (bits & ~63) | group_id -> 4 VALU/elem, no index
// shuffles until epilogue.
// __launch_bounds__ CAUTION (r3): 2nd arg >2 caps VGPR at 64 -> spills.
__global__ __launch_bounds__(256, 2) void argmin_kernel(
    const _Float16* __restrict__ xnh, const _Float16* __restrict__ ehg,
    const float* __restrict__ e2g,
    float* __restrict__ b1p, int* __restrict__ i1p,
    float* __restrict__ b2p, int* __restrict__ i2p)
{
  // [wave][ring][code 0..15][128 halfs]; within row n chunk slot kcs holds
  // global chunk kc = kcs ^ (n&7). 48KB + 4KB e2.
  __shared__ _Float16 ebuf[4][3][16][128];
  __shared__ float e2l[KSPLIT];

  int tid = threadIdx.x;
  int w = tid >> 6, L = tid & 63, c = L & 15, q = L >> 4;
  int bx = blockIdx.x;
  int mt = bx & (ROWS / MTILE - 1);   // 0..63
  int ns = bx >> 6;                   // 0..7  (grid 512)
  int rowbase = mt * MTILE + w * 64;
  int code0 = ns * KSPLIT;

  // A fragments (issued before the one barrier so their vmcnt drains there)
  half8 ah[4][4];
  #pragma unroll
  for (int g = 0; g < 4; ++g) {
    const _Float16* xr = xnh + (size_t)(rowbase + g * 16 + c) * DIM;
    #pragma unroll
    for (int ks = 0; ks < 4; ++ks)
      ah[g][ks] = *(const half8*)(xr + ks * 32 + q * 8);
  }

  // e2 -> LDS with +256 bias baked in (acc stays positive for key packing)
  {
    float4 v = ((const float4*)(e2g + code0))[tid];
    float4 o = {256.f + v.x, 256.f + v.y, 256.f + v.z, 256.f + v.w};
    ((float4*)e2l)[tid] = o;
  }
  __syncthreads();   // ONLY barrier: drains all vmem -> clean vmcnt baseline

  _Float16* wbase = &ebuf[w][0][0][0];
  // wave-private staging: one 16-code group = 4KB = 4 x (64 lanes x 16B)
  auto stage = [&](int g, int ring) {
    int cbase = code0 + g * 16;
    _Float16* lb = wbase + ring * (16 * 128);
    #pragma unroll
    for (int it = 0; it < 4; ++it) {
      int cid = it * 64 + L;             // 0..255
      int n   = cid >> 4;                // code row 0..15
      int kcs = cid & 15;                // LDS slot chunk
      int kc  = kcs ^ (n & 7);           // global chunk (inverse swizzle)
      async_copy16(ehg + (size_t)(cbase + n) * DIM + kc * 8, lb + cid * 8);
    }
  };
  stage(0, 0); stage(1, 1); stage(2, 2);

  unsigned k1[4][4], k2[4][4];
  #pragma unroll
  for (int g = 0; g < 4; ++g)
    #pragma unroll
    for (int r = 0; r < 4; ++r) { k1[g][r] = 0u; k2[g][r] = 0u; }

  for (int g = 0; g < NGROUP; ++g) {
    // wave-local wait: stage(g) landed; g+1,g+2 (8 loads) stay in flight
    if (g + 2 < NGROUP)      asm volatile("s_waitcnt vmcnt(8)" ::: "memory");
    else if (g + 1 < NGROUP) asm volatile("s_waitcnt vmcnt(4)" ::: "memory");
    else                     asm volatile("s_waitcnt vmcnt(0)" ::: "memory");

    const _Float16* buf = wbase + (g % 3) * (16 * 128);
    float e2v = e2l[(size_t)g * 16 + c];
    half8 bh[4];
    #pragma unroll
    for (int ks = 0; ks < 4; ++ks)
      bh[ks] = *(const half8*)(buf + (size_t)c * 128 + ((ks * 4 + q) ^ (c & 7)) * 8);

    unsigned gp = (unsigned)g;
    #pragma unroll
    for (int gg = 0; gg < 4; ++gg) {
      floatx4 acc = {e2v, e2v, e2v, e2v};
      #pragma unroll
      for (int ks = 0; ks < 4; ++ks)
        acc = __builtin_amdgcn_mfma_f32_16x16x32_f16(ah[gg][ks], bh[ks], acc, 0, 0, 0);
      #pragma unroll
      for (int r = 0; r < 4; ++r) {
        unsigned kk = (__float_as_uint(acc[r]) & 0xFFFFFFC0u) | gp;
        unsigned tt = kk < k1[gg][r] ? kk : k1[gg][r];     // min(kk, k1)
        k1[gg][r] = kk > k1[gg][r] ? kk : k1[gg][r];       // top-1
        k2[gg][r] = tt > k2[gg][r] ? tt : k2[gg][r];       // top-2
      }
    }
    // ds_reads of this buffer complete before its slot is restaged
    asm volatile("s_waitcnt lgkmcnt(0)" ::: "memory");
    if (g + 3 < NGROUP) stage(g + 3, g % 3);
  }

  // epilogue: unpack -> merge top-2 across the 16 c-lanes of each quad
  #pragma unroll
  for (int gg = 0; gg < 4; ++gg)
    #pragma unroll
    for (int r = 0; r < 4; ++r) {
      float s1 = __uint_as_float(k1[gg][r] & 0xFFFFFFC0u) - 256.f;
      float s2 = __uint_as_float(k2[gg][r] & 0xFFFFFFC0u) - 256.f;
      int   j1 = code0 + (int)(k1[gg][r] & 63u) * 16 + c;
      int   j2 = code0 + (int)(k2[gg][r] & 63u) * 16 + c;
      #pragma unroll
      for (int m = 1; m < 16; m <<= 1) {
        float o1 = __shfl_xor(s1, m); int oj1 = __shfl_xor(j1, m);
        float o2 = __shfl_xor(s2, m); int oj2 = __shfl_xor(j2, m);
        if (o1 > s1) {
          bool t = (s1 >= o2);
          s2 = t ? s1 : o2;  j2 = t ? j1 : oj2;
          s1 = o1; j1 = oj1;
        } else {
          bool t = (o1 >= s2);
          s2 = t ? o1 : s2;  j2 = t ? oj1 : j2;
        }
      }
      if (c == 0) {
        int row = rowbase + gg * 16 + q * 4 + r;
        b1p[(size_t)row * NSPLIT + ns] = s1; i1p[(size_t)row * NSPLIT + ns] = j1;
        b2p[(size_t)row * NSPLIT + ns] = s2; i2p[(size_t)row * NSPLIT + ns] = j2;
      }
    }
}

// ---------------- kernel 3: prefiltered exact rescore + gather + fused loss ----------------
// 16 candidates/row (8 splits x top-2); lane k = L&15 -> candidate, 4 lane
// copies each cover 32 dims. Prefilter skips candidates < max - DELTA.
__global__ __launch_bounds__(256) void gather_loss_kernel(
    const float* __restrict__ x, const float* __restrict__ cb,
    const float* __restrict__ e2g,
    const float* __restrict__ b1p, const int* __restrict__ i1p,
    const float* __restrict__ b2p, const int* __restrict__ i2p,
    float* __restrict__ out_q, float* __restrict__ out_ind,
    float* __restrict__ out_loss)
{
  __shared__ float lsum[4];
  int tid = threadIdx.x;
  int L = tid & 63;
  int w = tid >> 6;
  int row = blockIdx.x * 4 + w;

  int k  = L & 15;
  int qd = L >> 4;

  int ci = 0; float cv = -3.4e38f;
  if (L < 8)       { ci = i1p[(size_t)row * NSPLIT + L];       cv = b1p[(size_t)row * NSPLIT + L]; }
  else if (L < 16) { ci = i2p[(size_t)row * NSPLIT + (L - 8)]; cv = b2p[(size_t)row * NSPLIT + (L - 8)]; }
  int   idxk = __shfl(ci, k);
  float tvk  = __shfl(cv, k);

  float tmax = tvk;
  #pragma unroll
  for (int m = 1; m < 16; m <<= 1) tmax = fmaxf(tmax, __shfl_xor(tmax, m));
  bool keep = tvk >= tmax - DELTA;

  // LayerNorm stats (exact fp32)
  float2 xv = ((const float2*)(x + (size_t)row * DIM))[L];
  float s = xv.x + xv.y;
  #pragma unroll
  for (int m = 1; m < 64; m <<= 1) s += __shfl_xor(s, m);
  float mu = s * (1.0f / 128.0f);
  float dx = xv.x - mu, dy = xv.y - mu;
  float s2 = dx * dx + dy * dy;
  #pragma unroll
  for (int m = 1; m < 64; m <<= 1) s2 += __shfl_xor(s2, m);
  float rstd = 1.0f / sqrtf(s2 * (1.0f / 128.0f) + 1e-5f);

  // exact dot over this lane's 32-dim quarter (survivors only)
  float p = 0.f;
  if (keep) {
    const float4* xr4 = (const float4*)(x  + (size_t)row  * DIM);
    const float4* er4 = (const float4*)(cb + (size_t)idxk * DIM);
    #pragma unroll
    for (int j = 0; j < 8; ++j) {
      float4 a = xr4[qd * 8 + j];
      float4 e = er4[qd * 8 + j];
      p += (a.x - mu) * e.x + (a.y - mu) * e.y + (a.z - mu) * e.z + (a.w - mu) * e.w;
    }
    p *= rstd;
  }
  p += __shfl_xor(p, 16);
  p += __shfl_xor(p, 32);
  float t = keep ? p + e2g[idxk] : -3.4e38f;   // e2g = -0.5*||e||^2 exact

  int bi = idxk;
  #pragma unroll
  for (int m = 1; m < 16; m <<= 1) {
    float ot = __shfl_xor(t, m);
    int   oi = __shfl_xor(bi, m);
    if (ot > t || (ot == t && oi < bi)) { t = ot; bi = oi; }
  }

  float2 qv = ((const float2*)(cb + (size_t)bi * DIM))[L];
  ((float2*)out_q)[(size_t)row * 64 + L] = qv;
  float xn0 = dx * rstd, xn1 = dy * rstd;
  float e0 = qv.x - xn0, e1 = qv.y - xn1;
  float le = e0 * e0 + e1 * e1;
  #pragma unroll
  for (int m = 1; m < 64; m <<= 1) le += __shfl_xor(le, m);
  if (L == 0) {
    lsum[w] = le;
    out_ind[row] = (float)bi;
  }
  __syncthreads();
  if (tid == 0)
    atomicAdd(out_loss, (lsum[0] + lsum[1] + lsum[2] + lsum[3]) * (1.0f / ((float)ROWS * DIM)));
}

extern "C" void kernel_launch(void* const* d_in, const int* in_sizes, int n_in,
                              void* d_out, int out_size, void* d_ws, size_t ws_size,
                              hipStream_t stream)
{
  const float* x  = (const float*)d_in[0];   // [4,4096,128] fp32
  const float* cb = (const float*)d_in[1];   // [8192,128]  fp32

  char* ws = (char*)d_ws;
  _Float16* ehg = (_Float16*)(ws + 0);        // 2 MB
  float*    e2g = (float*)   (ws + 2097152);  // 32 KB
  float*    b1p = (float*)   (ws + 2129920);  // 512 KB
  int*      i1p = (int*)     (ws + 2654208);  // 512 KB
  float*    b2p = (float*)   (ws + 3178496);  // 512 KB
  int*      i2p = (int*)     (ws + 3702784);  // 512 KB

  float* out_q    = (float*)d_out;                   // 16384*128
  float* out_ind  = out_q + (size_t)ROWS * DIM;      // 16384 (as float)
  float* out_loss = out_ind + ROWS;                  // 1

  // xnh (fp16 LN output, 4 MB) lives in the out_q region: written by prep,
  // read by argmin; out_q is only written afterwards by gather.
  _Float16* xnh = (_Float16*)out_q;

  prep_kernel<<<KCODES / 4 + ROWS / 4, 256, 0, stream>>>(cb, x, ehg, e2g, xnh, out_loss);
  argmin_kernel<<<(ROWS / MTILE) * NSPLIT, 256, 0, stream>>>(xnh, ehg, e2g, b1p, i1p, b2p, i2p);
  gather_loss_kernel<<<ROWS / 4, 256, 0, stream>>>(x, cb, e2g, b1p, i1p, b2p, i2p, out_q, out_ind, out_loss);
}

// Round 7
// 180.479 us; speedup vs baseline: 1.0110x; 1.0110x over previous
//
#include <hip/hip_runtime.h>
#include <hip/hip_fp16.h>
#include <math.h>

typedef _Float16 half8  __attribute__((ext_vector_type(8)));
typedef _Float16 half2v __attribute__((ext_vector_type(2)));
typedef float   floatx4 __attribute__((ext_vector_type(4)));

#define ROWS   16384
#define DIM    128
#define KCODES 8192
#define NSPLIT 16
#define KSPLIT (KCODES / NSPLIT)   // 512 codes per split
#define NGROUP (KSPLIT / 16)       // 32 groups of 16 codes
#define MTILE  256                 // rows per block (4 waves x 64)
#define THR    0.3f                // decisive margin > 2*pass1 err (~0.2)

__device__ __forceinline__ void async_copy16(const void* src, void* dst_lds) {
  __builtin_amdgcn_global_load_lds((const __attribute__((address_space(1))) void*)src,
                                   (__attribute__((address_space(3))) void*)dst_lds,
                                   16, 0, 0);
}

// ---------------- kernel 1: codebook fp16 + e2, LN-once -> xnh ----------------
__global__ __launch_bounds__(256) void prep_kernel(
    const float* __restrict__ cb, const float* __restrict__ x,
    _Float16* __restrict__ ehg, float* __restrict__ e2g,
    _Float16* __restrict__ xnh, float* __restrict__ out_loss)
{
  int tid = threadIdx.x;
  int L = tid & 63;
  int bx = blockIdx.x;
  if (bx == 0 && tid == 0) *out_loss = 0.f;   // gather accumulates atomically
  if (bx < KCODES / 4) {
    int row = bx * 4 + (tid >> 6);
    float2 v = ((const float2*)(cb + (size_t)row * DIM))[L];
    float s2 = v.x * v.x + v.y * v.y;
    #pragma unroll
    for (int m = 1; m < 64; m <<= 1) s2 += __shfl_xor(s2, m);
    if (L == 0) e2g[row] = -0.5f * s2;
    half2v hi = {(_Float16)v.x, (_Float16)v.y};
    ((half2v*)(ehg + (size_t)row * DIM))[L] = hi;
  } else {
    int row = (bx - KCODES / 4) * 4 + (tid >> 6);
    float2 xv = ((const float2*)(x + (size_t)row * DIM))[L];
    float s = xv.x + xv.y;
    #pragma unroll
    for (int m = 1; m < 64; m <<= 1) s += __shfl_xor(s, m);
    float mu = s * (1.0f / 128.0f);
    float dx = xv.x - mu, dy = xv.y - mu;
    float s2 = dx * dx + dy * dy;
    #pragma unroll
    for (int m = 1; m < 64; m <<= 1) s2 += __shfl_xor(s2, m);
    float rstd = 1.0f / sqrtf(s2 * (1.0f / 128.0f) + 1e-5f);
    half2v hv = {(_Float16)(dx * rstd), (_Float16)(dy * rstd)};
    ((half2v*)(xnh + (size_t)row * DIM))[L] = hv;
  }
}

// ---------------- kernel 2: barrier-free argmin ----------------
// r6 post-mortem: barrier-free wave-private rings took argmin 100->65.5us but
// grid 512 = exactly 2 blocks/CU capped TLP (occupancy 17%, both pipes idle).
// This round: 2-ring (32KB) + NSPLIT=16 -> grid 1024 = 4 blocks/CU
// (LDS 34KB x4 = 136KB <= 160KB; VGPR ~80 x 4 waves/SIMD <= 512).
// Wave-local counted s_waitcnt vmcnt only; NO __syncthreads in the loop.
// Packed top-2: acc pre-biased to 256-e2/2 (>0), key=(bits&~63)|group ->
// 4 VALU/elem. Staging addresses hoisted out of the loop.
// __launch_bounds__ CAUTION (r3): 2nd arg >2 caps VGPR at 64 -> spills.
__global__ __launch_bounds__(256, 2) void argmin_kernel(
    const _Float16* __restrict__ xnh, const _Float16* __restrict__ ehg,
    const float* __restrict__ e2g,
    float* __restrict__ b1p, int* __restrict__ i1p,
    float* __restrict__ b2p, int* __restrict__ i2p)
{
  // [wave][ring][code 0..15][128 halfs]; within row n chunk slot kcs holds
  // global chunk kc = kcs ^ (n&7). 32KB + 2KB e2.
  __shared__ _Float16 ebuf[4][2][16][128];
  __shared__ float e2l[KSPLIT];

  int tid = threadIdx.x;
  int w = tid >> 6, L = tid & 63, c = L & 15, q = L >> 4;
  int bx = blockIdx.x;
  int mt = bx & (ROWS / MTILE - 1);   // 0..63
  int ns = bx >> 6;                   // 0..15  (grid 1024)
  int rowbase = mt * MTILE + w * 64;
  int code0 = ns * KSPLIT;

  // A fragments (issued before the one barrier so their vmcnt drains there)
  half8 ah[4][4];
  #pragma unroll
  for (int g = 0; g < 4; ++g) {
    const _Float16* xr = xnh + (size_t)(rowbase + g * 16 + c) * DIM;
    #pragma unroll
    for (int ks = 0; ks < 4; ++ks)
      ah[g][ks] = *(const half8*)(xr + ks * 32 + q * 8);
  }

  // e2 -> LDS with +256 bias baked in (acc stays positive for key packing)
  if (tid < KSPLIT / 4) {
    float4 v = ((const float4*)(e2g + code0))[tid];
    float4 o = {256.f + v.x, 256.f + v.y, 256.f + v.z, 256.f + v.w};
    ((float4*)e2l)[tid] = o;
  }

  // hoisted wave-private staging addresses (group-0 bases)
  const _Float16* gsrc[4];
  _Float16*       ldst[2][4];
  #pragma unroll
  for (int it = 0; it < 4; ++it) {
    int cid = it * 64 + L;             // 0..255
    int n   = cid >> 4;                // code row 0..15
    int kcs = cid & 15;                // LDS slot chunk
    int kc  = kcs ^ (n & 7);           // global chunk (inverse swizzle)
    gsrc[it]    = ehg + (size_t)(code0 + n) * DIM + kc * 8;
    ldst[0][it] = &ebuf[w][0][0][0] + cid * 8;
    ldst[1][it] = &ebuf[w][1][0][0] + cid * 8;
  }
  __syncthreads();   // ONLY barrier: e2l visible + clean vmcnt baseline

  auto stage = [&](int g, int ring) {
    #pragma unroll
    for (int it = 0; it < 4; ++it)
      async_copy16(gsrc[it] + (size_t)g * 16 * DIM, ldst[ring][it]);
  };
  stage(0, 0); stage(1, 1);

  unsigned k1[4][4], k2[4][4];
  #pragma unroll
  for (int g = 0; g < 4; ++g)
    #pragma unroll
    for (int r = 0; r < 4; ++r) { k1[g][r] = 0u; k2[g][r] = 0u; }

  for (int g = 0; g < NGROUP; ++g) {
    // wave-local wait: stage(g) landed; stage(g+1)'s 4 loads stay in flight
    if (g + 1 < NGROUP) asm volatile("s_waitcnt vmcnt(4)" ::: "memory");
    else                asm volatile("s_waitcnt vmcnt(0)" ::: "memory");

    const _Float16* buf = &ebuf[w][g & 1][0][0];
    float e2v = e2l[(size_t)g * 16 + c];
    half8 bh[4];
    #pragma unroll
    for (int ks = 0; ks < 4; ++ks)
      bh[ks] = *(const half8*)(buf + (size_t)c * 128 + ((ks * 4 + q) ^ (c & 7)) * 8);

    unsigned gp = (unsigned)g;
    #pragma unroll
    for (int gg = 0; gg < 4; ++gg) {
      floatx4 acc = {e2v, e2v, e2v, e2v};
      #pragma unroll
      for (int ks = 0; ks < 4; ++ks)
        acc = __builtin_amdgcn_mfma_f32_16x16x32_f16(ah[gg][ks], bh[ks], acc, 0, 0, 0);
      #pragma unroll
      for (int r = 0; r < 4; ++r) {
        unsigned kk = (__float_as_uint(acc[r]) & 0xFFFFFFC0u) | gp;
        unsigned tt = kk < k1[gg][r] ? kk : k1[gg][r];     // min(kk, k1)
        k1[gg][r] = kk > k1[gg][r] ? kk : k1[gg][r];       // top-1
        k2[gg][r] = tt > k2[gg][r] ? tt : k2[gg][r];       // top-2
      }
    }
    if (g + 2 < NGROUP) {
      // ds_reads of this ring retire before global_load_lds rewrites it
      asm volatile("s_waitcnt lgkmcnt(0)" ::: "memory");
      stage(g + 2, g & 1);
    }
  }

  // epilogue: unpack -> merge top-2 across the 16 c-lanes of each quad
  #pragma unroll
  for (int gg = 0; gg < 4; ++gg)
    #pragma unroll
    for (int r = 0; r < 4; ++r) {
      float s1 = __uint_as_float(k1[gg][r] & 0xFFFFFFC0u) - 256.f;
      float s2 = __uint_as_float(k2[gg][r] & 0xFFFFFFC0u) - 256.f;
      int   j1 = code0 + (int)(k1[gg][r] & 63u) * 16 + c;
      int   j2 = code0 + (int)(k2[gg][r] & 63u) * 16 + c;
      #pragma unroll
      for (int m = 1; m < 16; m <<= 1) {
        float o1 = __shfl_xor(s1, m); int oj1 = __shfl_xor(j1, m);
        float o2 = __shfl_xor(s2, m); int oj2 = __shfl_xor(j2, m);
        if (o1 > s1) {
          bool t = (s1 >= o2);
          s2 = t ? s1 : o2;  j2 = t ? j1 : oj2;
          s1 = o1; j1 = oj1;
        } else {
          bool t = (o1 >= s2);
          s2 = t ? o1 : s2;  j2 = t ? oj1 : j2;
        }
      }
      if (c == 0) {
        int row = rowbase + gg * 16 + q * 4 + r;
        b1p[(size_t)row * NSPLIT + ns] = s1; i1p[(size_t)row * NSPLIT + ns] = j1;
        b2p[(size_t)row * NSPLIT + ns] = s2; i2p[(size_t)row * NSPLIT + ns] = j2;
      }
    }
}

// ---------------- kernel 3: fast-path rescore + gather + fused loss ----------------
// 32 candidates/row (16 splits x top-2). Pass-1 scores are exact to E~0.1
// (fp16 dot + key truncation). If the pass-1 max beats every other candidate
// by THR=0.3 > 2E, the winner is provable WITHOUT any exact dot (most rows).
// Ambiguous rows: exact fp32 rescore of survivors within THR of the max.
__global__ __launch_bounds__(256) void gather_loss_kernel(
    const float* __restrict__ x, const float* __restrict__ cb,
    const float* __restrict__ e2g,
    const float* __restrict__ b1p, const int* __restrict__ i1p,
    const float* __restrict__ b2p, const int* __restrict__ i2p,
    float* __restrict__ out_q, float* __restrict__ out_ind,
    float* __restrict__ out_loss)
{
  __shared__ float lsum[4];
  int tid = threadIdx.x;
  int L = tid & 63;
  int w = tid >> 6;
  int row = blockIdx.x * 4 + w;

  int k  = L & 31;
  int qd = L >> 5;

  // lanes 0..15: split L top-1; lanes 16..31: split (L-16) top-2
  int ci = 0; float cv = -3.4e38f;
  if (L < 16)      { ci = i1p[(size_t)row * NSPLIT + L];        cv = b1p[(size_t)row * NSPLIT + L]; }
  else if (L < 32) { ci = i2p[(size_t)row * NSPLIT + (L - 16)]; cv = b2p[(size_t)row * NSPLIT + (L - 16)]; }
  int   idxk = __shfl(ci, k);
  float tvk  = __shfl(cv, k);

  float tmax = tvk;
  #pragma unroll
  for (int m = 1; m < 32; m <<= 1) tmax = fmaxf(tmax, __shfl_xor(tmax, m));
  bool keep = tvk >= tmax - THR;
  unsigned long long mb = __ballot(keep);   // 2 set bits per surviving candidate

  // LayerNorm stats (exact fp32) -- needed for loss regardless of path
  float2 xv = ((const float2*)(x + (size_t)row * DIM))[L];
  float s = xv.x + xv.y;
  #pragma unroll
  for (int m = 1; m < 64; m <<= 1) s += __shfl_xor(s, m);
  float mu = s * (1.0f / 128.0f);
  float dx = xv.x - mu, dy = xv.y - mu;
  float s2 = dx * dx + dy * dy;
  #pragma unroll
  for (int m = 1; m < 64; m <<= 1) s2 += __shfl_xor(s2, m);
  float rstd = 1.0f / sqrtf(s2 * (1.0f / 128.0f) + 1e-5f);

  int bi;
  if (__popcll(mb) == 2) {
    // decisive: the unique survivor is the exact winner
    int lsel = (int)__ffsll(mb) - 1;
    bi = __shfl(idxk, lsel);
  } else {
    // exact dot over this lane's 64-dim half of candidate idxk (survivors)
    float p = 0.f;
    if (keep) {
      const float4* xr4 = (const float4*)(x  + (size_t)row  * DIM);
      const float4* er4 = (const float4*)(cb + (size_t)idxk * DIM);
      #pragma unroll
      for (int j = 0; j < 16; ++j) {
        float4 a = xr4[qd * 16 + j];
        float4 e = er4[qd * 16 + j];
        p += (a.x - mu) * e.x + (a.y - mu) * e.y + (a.z - mu) * e.z + (a.w - mu) * e.w;
      }
      p *= rstd;
    }
    p += __shfl_xor(p, 32);                    // both halves share 'keep'
    float t = keep ? p + e2g[idxk] : -3.4e38f; // e2g = -0.5*||e||^2 exact
    bi = idxk;
    #pragma unroll
    for (int m = 1; m < 32; m <<= 1) {
      float ot = __shfl_xor(t, m);
      int   oi = __shfl_xor(bi, m);
      if (ot > t || (ot == t && oi < bi)) { t = ot; bi = oi; }
    }
  }

  float2 qv = ((const float2*)(cb + (size_t)bi * DIM))[L];
  ((float2*)out_q)[(size_t)row * 64 + L] = qv;
  float xn0 = dx * rstd, xn1 = dy * rstd;
  float e0 = qv.x - xn0, e1 = qv.y - xn1;
  float le = e0 * e0 + e1 * e1;
  #pragma unroll
  for (int m = 1; m < 64; m <<= 1) le += __shfl_xor(le, m);
  if (L == 0) {
    lsum[w] = le;
    out_ind[row] = (float)bi;
  }
  __syncthreads();
  if (tid == 0)
    atomicAdd(out_loss, (lsum[0] + lsum[1] + lsum[2] + lsum[3]) * (1.0f / ((float)ROWS * DIM)));
}

extern "C" void kernel_launch(void* const* d_in, const int* in_sizes, int n_in,
                              void* d_out, int out_size, void* d_ws, size_t ws_size,
                              hipStream_t stream)
{
  const float* x  = (const float*)d_in[0];   // [4,4096,128] fp32
  const float* cb = (const float*)d_in[1];   // [8192,128]  fp32

  char* ws = (char*)d_ws;
  _Float16* ehg = (_Float16*)(ws + 0);        // 2 MB
  float*    e2g = (float*)   (ws + 2097152);  // 32 KB
  float*    b1p = (float*)   (ws + 2129920);  // 1 MB
  int*      i1p = (int*)     (ws + 3178496);  // 1 MB
  float*    b2p = (float*)   (ws + 4227072);  // 1 MB
  int*      i2p = (int*)     (ws + 5275648);  // 1 MB

  float* out_q    = (float*)d_out;                   // 16384*128
  float* out_ind  = out_q + (size_t)ROWS * DIM;      // 16384 (as float)
  float* out_loss = out_ind + ROWS;                  // 1

  // xnh (fp16 LN output, 4 MB) lives in the out_q region: written by prep,
  // read by argmin; out_q is only written afterwards by gather.
  _Float16* xnh = (_Float16*)out_q;

  prep_kernel<<<KCODES / 4 + ROWS / 4, 256, 0, stream>>>(cb, x, ehg, e2g, xnh, out_loss);
  argmin_kernel<<<(ROWS / MTILE) * NSPLIT, 256, 0, stream>>>(xnh, ehg, e2g, b1p, i1p, b2p, i2p);
  gather_loss_kernel<<<ROWS / 4, 256, 0, stream>>>(x, cb, e2g, b1p, i1p, b2p, i2p, out_q, out_ind, out_loss);
}